// Round 5
// baseline (636.392 us; speedup 1.0000x reference)
//
#include <hip/hip_runtime.h>

// Problem constants (B=2, H=16, L=2048, D=64 — fixed by the reference setup).
#define BH   32
#define LSEQ 2048
#define DDIM 64
#define ERRC 1e-12f
#define SROW 136   // LDS strip row stride in floats: 128 cols + 8 pad -> 16B-aligned rows,
                   // bank rotation 8 words/row (<=4-way write conflict, full-BW flush read)

typedef __attribute__((ext_vector_type(8)))  short bf16x8;
typedef __attribute__((ext_vector_type(4)))  float floatx4;
typedef __attribute__((ext_vector_type(4)))  unsigned short ushort4v;

// float -> bf16 round-to-nearest-even (inputs are finite, no NaN handling needed)
__device__ __forceinline__ unsigned short f2bf(float f) {
    unsigned u = __float_as_uint(f);
    u = u + 0x7FFFu + ((u >> 16) & 1u);
    return (unsigned short)(u >> 16);
}

__device__ __forceinline__ bf16x8 pack8s(const float* __restrict__ p, float w) {
    const floatx4* pv = (const floatx4*)p;
    floatx4 x = pv[0], y = pv[1];
    bf16x8 r;
    r[0] = (short)f2bf(x[0] * w); r[1] = (short)f2bf(x[1] * w);
    r[2] = (short)f2bf(x[2] * w); r[3] = (short)f2bf(x[3] * w);
    r[4] = (short)f2bf(y[0] * w); r[5] = (short)f2bf(y[1] * w);
    r[6] = (short)f2bf(y[2] * w); r[7] = (short)f2bf(y[3] * w);
    return r;
}

// Prep: ks = bf16(k * sqrt(src+err)), kd = bf16(k * sqrt(dest+err)).
__global__ __launch_bounds__(256) void prep_scaled(const float* __restrict__ k,
                                                   const float* __restrict__ src,
                                                   const float* __restrict__ dest,
                                                   unsigned short* __restrict__ ks,
                                                   unsigned short* __restrict__ kd) {
    int idx4 = blockIdx.x * 256 + threadIdx.x;
    int row  = idx4 >> 4;                     // 16 float4 per 64-wide row
    float s = sqrtf(src[row] + ERRC);
    float d = sqrtf(dest[row] + ERRC);
    floatx4 v = ((const floatx4*)k)[idx4];
    ushort4v os, od;
#pragma unroll
    for (int r = 0; r < 4; ++r) { os[r] = f2bf(v[r] * s); od[r] = f2bf(v[r] * d); }
    ((ushort4v*)ks)[idx4] = os;
    ((ushort4v*)kd)[idx4] = od;
}

// Load one 16-row MFMA operand fragment pair (K=64 split as k<32 / k>=32).
// Layout for 16x16x32: row = lane&15, k = (lane>>4)*8 + t.
template<bool RAW>
__device__ __forceinline__ void load_row16(const void* __restrict__ kp, long base, int row,
                                           int q, const float* __restrict__ w, int bhL,
                                           bf16x8& lo, bf16x8& hi) {
    if (RAW) {
        const float* p = (const float*)kp + base + (long)row * DDIM + q * 8;
        float s = sqrtf(w[bhL + row] + ERRC);
        lo = pack8s(p, s);
        hi = pack8s(p + 32, s);
    } else {
        const unsigned short* p = (const unsigned short*)kp + base + (long)row * DDIM + q * 8;
        lo = *(const bf16x8*)p;
        hi = *(const bf16x8*)(p + 32);
    }
}

// One wave = one 16-column i-tile; streams 32 groups of 64 j (4 16-row tiles),
// staging each 16x128 output strip in wave-private LDS, then flushing with
// 8 NONTEMPORAL stores of 2 rows x 512B lane-contiguous (full 128B lines per
// instruction -> no partial-line RMW; bypasses L2 so the DRAM stream is
// issue-ordered 512B bursts, not eviction-ordered 128B lines).
// Swapped MFMA: D = kd_tile(j rows) . ks_rows(i)^T -> D[m=j][n=i],
// C/D: col(l16)=i, row(q*4+r)=j -> each lane holds 4 CONSECUTIVE j per tile, in-lane.
template<bool RAW>
__global__ __launch_bounds__(256, 4) void mha_fused6(const void* __restrict__ ka,  // kd (or raw k)
                                                     const void* __restrict__ kb,  // ks (or raw k)
                                                     const float* __restrict__ src,
                                                     const float* __restrict__ dest,
                                                     float* __restrict__ out) {
    __shared__ float strip[4][16 * SROW];     // 8.5 KiB per wave, wave-private (no barriers)
    const int tid  = threadIdx.x;
    const int wave = tid >> 6;
    const int lane = tid & 63;
    const int q    = lane >> 4;
    const int l16  = lane & 15;
    // bh in low bits: same-bh blocks are 32 apart -> same XCD under mod-8 dispatch.
    const int bh = blockIdx.x & 31;
    const int ib = blockIdx.x >> 5;           // 0..31
    const int i0 = (ib * 4 + wave) * 16;      // this wave's 16-column (i) tile
    const int bhL = bh * LSEQ;
    const long base = (long)bh * LSEQ * DDIM;
    float* sw = strip[wave];

    // B operand: ks row i0+l16, held for the whole kernel
    bf16x8 blo, bhi;
    load_row16<RAW>(kb, base, i0 + l16, q, src, bhL, blo, bhi);

    float carry = 0.f;                        // running row sum for output row i0+l16
    const float c23 = 2.0f / 3.0f;

    // prefetch j-tiles 0..3
    bf16x8 aLo[4], aHi[4];
#pragma unroll
    for (int t = 0; t < 4; ++t)
        load_row16<RAW>(ka, base, 16 * t + l16, q, dest, bhL, aLo[t], aHi[t]);

    // flush mapping: lanes 0..31 -> row 2s, lanes 32..63 -> row 2s+1; 4 cols/lane
    const int h2  = lane >> 5;
    const int c32 = lane & 31;
    float* obase = out + (long)(bhL + i0 + h2) * LSEQ + 4 * c32;
    const int lrd = h2 * SROW + 4 * c32;

    for (int sup = 0; sup < 16; ++sup) {
        const int j0s = sup << 7;             // strip base (128 cols)
        const bool maskedStrip = (j0s + 128) <= i0;

#pragma unroll
        for (int half = 0; half < 2; ++half) {
            const int j0 = j0s + (half << 6);
            const int colbase = half << 6;

            // prefetch next group's 4 tiles (redundant reload of tiles 0..3 at the end)
            bf16x8 nLo[4], nHi[4];
            const int jn = (j0 + 64 < LSEQ) ? (j0 + 64) : 0;
#pragma unroll
            for (int t = 0; t < 4; ++t)
                load_row16<RAW>(ka, base, jn + 16 * t + l16, q, dest, bhL, nLo[t], nHi[t]);

            // 8 MFMAs, independent across the 4 tiles
            floatx4 acc[4];
#pragma unroll
            for (int t = 0; t < 4; ++t) {
                floatx4 z4 = {0.f, 0.f, 0.f, 0.f};
                z4 = __builtin_amdgcn_mfma_f32_16x16x32_bf16(aLo[t], blo, z4, 0, 0, 0);
                acc[t] = __builtin_amdgcn_mfma_f32_16x16x32_bf16(aHi[t], bhi, z4, 0, 0, 0);
            }

            // a3 = exp2(log2(relu(a1)+err) * 2/3) — 16 independent elements
            float u[4][4];
#pragma unroll
            for (int t = 0; t < 4; ++t)
#pragma unroll
                for (int r = 0; r < 4; ++r) {
                    float v = fmaxf(acc[t][r], 0.f) + ERRC;
                    u[t][r] = exp2f(c23 * __log2f(v));
                }

            if (j0 + 64 <= i0) {
                // all 4 tiles fully below the diagonal: only the strip total feeds carry
                float s = 0.f;
#pragma unroll
                for (int t = 0; t < 4; ++t)
                    s += (u[t][0] + u[t][1]) + (u[t][2] + u[t][3]);
                float s1 = s + __shfl_xor(s, 16, 64);
                carry += s1 + __shfl_xor(s1, 32, 64);
                if (!maskedStrip) {           // mixed strip: stage the zeros for the flush
                    const floatx4 z = {0.f, 0.f, 0.f, 0.f};
#pragma unroll
                    for (int t = 0; t < 4; ++t)
                        *(floatx4*)&sw[l16 * SROW + colbase + 16 * t + 4 * q] = z;
                }
            } else {
#pragma unroll
                for (int t = 0; t < 4; ++t) {
                    const int jt0 = j0 + 16 * t;
                    float* dst = &sw[l16 * SROW + colbase + 16 * t + 4 * q];
                    if (jt0 + 16 <= i0) {
                        // fully masked tile: total only
                        float s = (u[t][0] + u[t][1]) + (u[t][2] + u[t][3]);
                        float s1 = s + __shfl_xor(s, 16, 64);
                        carry += s1 + __shfl_xor(s1, 32, 64);
                        const floatx4 z = {0.f, 0.f, 0.f, 0.f};
                        *(floatx4*)dst = z;
                    } else {
                        // in-lane inclusive prefix over this lane's 4 consecutive j
                        u[t][1] += u[t][0];
                        u[t][2] += u[t][1];
                        u[t][3] += u[t][2];
                        const float S   = u[t][3];
                        const float x16 = __shfl_xor(S, 16, 64);
                        const float s1  = S + x16;
                        const float x32 = __shfl_xor(s1, 32, 64);
                        // exclusive prefix over the 4 q-chunks + running carry
                        const float E = ((q & 1) ? x16 : 0.f) + ((q & 2) ? x32 : 0.f) + carry;
                        carry += s1 + x32;    // tile total — identical across the group
                        floatx4 o;
                        if (jt0 == i0) {      // the single mixed (diagonal) tile
#pragma unroll
                            for (int r = 0; r < 4; ++r)
                                o[r] = ((q * 4 + r) >= l16) ? (u[t][r] + E) : 0.f;
                        } else {              // fully above diagonal
#pragma unroll
                            for (int r = 0; r < 4; ++r)
                                o[r] = u[t][r] + E;
                        }
                        *(floatx4*)dst = o;
                    }
                }
            }

#pragma unroll
            for (int t = 0; t < 4; ++t) { aLo[t] = nLo[t]; aHi[t] = nHi[t]; }
        }

        // Flush the 16x128 strip: 8 nt instrs, each 2 rows x 512B lane-contiguous.
        // Every 128B line is fully covered by a single instruction -> clean full-line
        // nt writes, DRAM stream in issue order (not L2-eviction order).
        float* og = obase + j0s;
        if (maskedStrip) {
            const floatx4 z = {0.f, 0.f, 0.f, 0.f};
#pragma unroll
            for (int s = 0; s < 8; ++s)
                __builtin_nontemporal_store(z, (floatx4*)(og + (long)(2 * s) * LSEQ));
        } else {
#pragma unroll
            for (int s = 0; s < 8; ++s) {
                floatx4 v = *(const floatx4*)&sw[lrd + 2 * s * SROW];
                __builtin_nontemporal_store(v, (floatx4*)(og + (long)(2 * s) * LSEQ));
            }
        }
    }
}

extern "C" void kernel_launch(void* const* d_in, const int* in_sizes, int n_in,
                              void* d_out, int out_size, void* d_ws, size_t ws_size,
                              hipStream_t stream) {
    const float* k    = (const float*)d_in[0];
    const float* src  = (const float*)d_in[1];
    const float* dest = (const float*)d_in[2];
    float* out = (float*)d_out;

    const size_t half = (size_t)BH * LSEQ * DDIM * sizeof(unsigned short); // 8 MiB
    if (ws_size >= 2 * half) {
        unsigned short* ks = (unsigned short*)d_ws;
        unsigned short* kd = (unsigned short*)((char*)d_ws + half);
        prep_scaled<<<dim3(4096), dim3(256), 0, stream>>>(k, src, dest, ks, kd);
        mha_fused6<false><<<dim3(1024), dim3(256), 0, stream>>>(kd, ks, src, dest, out);
    } else {
        mha_fused6<true><<<dim3(1024), dim3(256), 0, stream>>>(k, k, src, dest, out);
    }
}